// Round 1
// baseline (194.254 us; speedup 1.0000x reference)
//
#include <hip/hip_runtime.h>

// Problem: B=16, PATCH_NUM=32, PATCH_SIZE=128, H=8, E=64, WIN=4096
// out[b,l,h,e] = V_inter[b, l>>7, h, e] + V_intra[b, l>>5, h, e]
// where V_* are full-softmax attentions (scale = 1/8) over L=32 / L=128.

#define NH 8
#define NE 64
#define ROWSTRIDE (NH * NE)   // 512 floats between consecutive l for fixed (b,h)

__device__ __forceinline__ float dot4(const float4 a, const float4 b) {
    return a.x * b.x + a.y * b.y + a.z * b.z + a.w * b.w;
}

// One block = (b, h, tile-of-32-query-rows). Block = 256 threads.
// FUSED=false: write attention output rows to dst (V_inter workspace, [B,32,H,E]).
// FUSED=true : intra path; dst = out. Each query row i is written to the 32
//              output rows l = i*32+j with vinter[b, i>>2, h, :] added.
template <int L, bool FUSED>
__global__ __launch_bounds__(256) void attn_kernel(
    const float* __restrict__ qg_, const float* __restrict__ kg_,
    const float* __restrict__ vg_, float* __restrict__ dst,
    const float* __restrict__ vinter)
{
    constexpr int TILES = L / 32;   // row tiles per (b,h)
    constexpr int CPT   = L / 32;   // score cols per thread
    constexpr int SST   = L + 1;    // score row stride (conflict-free)
    constexpr int KST   = 68;       // K/V/Q row stride (float4-aligned padding)

    __shared__ __align__(16) float Ks[L * KST];
    __shared__ __align__(16) float Vs[L * KST];
    __shared__ __align__(16) float Qs[32 * KST];
    __shared__ float S[32 * SST];

    const int tid  = threadIdx.x;
    const int bid  = blockIdx.x;
    const int tile = bid % TILES;
    const int h    = (bid / TILES) % NH;
    const int b    = bid / (TILES * NH);
    const int r0   = tile * 32;

    const float* kg = kg_ + ((size_t)b * L * NH + h) * NE;
    const float* vg = vg_ + ((size_t)b * L * NH + h) * NE;
    const float* qg = qg_ + ((size_t)(b * L + r0) * NH + h) * NE;

    // ---- stage K, V (all L rows) and Q (32 rows) into LDS ----
    for (int idx = tid; idx < L * 16; idx += 256) {
        const int row = idx >> 4;
        const int f   = (idx & 15) * 4;
        *(float4*)&Ks[row * KST + f] = *(const float4*)(kg + (size_t)row * ROWSTRIDE + f);
        *(float4*)&Vs[row * KST + f] = *(const float4*)(vg + (size_t)row * ROWSTRIDE + f);
    }
    for (int idx = tid; idx < 32 * 16; idx += 256) {
        const int row = idx >> 4;
        const int f   = (idx & 15) * 4;
        *(float4*)&Qs[row * KST + f] = *(const float4*)(qg + (size_t)row * ROWSTRIDE + f);
    }
    __syncthreads();

    // ---- scores: 32 rows x L cols, thread = 4 rows x CPT cols ----
    {
        const int rg = tid >> 5;        // 0..7 -> rows rg*4..rg*4+3
        const int cg = tid & 31;        // cols cg*CPT..cg*CPT+CPT-1
        const int rr = rg * 4;
        const int c0 = cg * CPT;
        float acc[4][CPT];
        #pragma unroll
        for (int i = 0; i < 4; i++)
            #pragma unroll
            for (int j = 0; j < CPT; j++) acc[i][j] = 0.f;

        #pragma unroll
        for (int e = 0; e < NE; e += 4) {
            float4 qv[4], kv[CPT];
            #pragma unroll
            for (int i = 0; i < 4; i++) qv[i] = *(const float4*)&Qs[(rr + i) * KST + e];
            #pragma unroll
            for (int j = 0; j < CPT; j++) kv[j] = *(const float4*)&Ks[(c0 + j) * KST + e];
            #pragma unroll
            for (int i = 0; i < 4; i++)
                #pragma unroll
                for (int j = 0; j < CPT; j++)
                    acc[i][j] += dot4(qv[i], kv[j]);
        }
        #pragma unroll
        for (int i = 0; i < 4; i++)
            #pragma unroll
            for (int j = 0; j < CPT; j++)
                S[(rr + i) * SST + c0 + j] = acc[i][j] * 0.125f;  // 1/sqrt(64)
    }
    __syncthreads();

    // ---- softmax: thread (r = tid>>3, sub = tid&7); redundant row scans ----
    const int r   = tid >> 3;
    const int sub = tid & 7;
    float m = -1e30f;
    for (int c = 0; c < L; c++) m = fmaxf(m, S[r * SST + c]);
    float sum = 0.f;
    for (int c = 0; c < L; c++) sum += __expf(S[r * SST + c] - m);
    const float inv = 1.f / sum;
    __syncthreads();              // everyone done reading raw scores
    for (int c = sub; c < L; c += 8)
        S[r * SST + c] = __expf(S[r * SST + c] - m);   // unnormalized p
    __syncthreads();

    // ---- PV: thread (r, sub) computes out[r][e0..e0+7] ----
    const int e0 = sub * 8;
    float a0=0,a1=0,a2=0,a3=0,a4=0,a5=0,a6=0,a7=0;
    for (int c = 0; c < L; c++) {
        const float p  = S[r * SST + c];
        const float4 va = *(const float4*)&Vs[c * KST + e0];
        const float4 vb = *(const float4*)&Vs[c * KST + e0 + 4];
        a0 += p * va.x; a1 += p * va.y; a2 += p * va.z; a3 += p * va.w;
        a4 += p * vb.x; a5 += p * vb.y; a6 += p * vb.z; a7 += p * vb.w;
    }
    float4 oA = make_float4(a0 * inv, a1 * inv, a2 * inv, a3 * inv);
    float4 oB = make_float4(a4 * inv, a5 * inv, a6 * inv, a7 * inv);

    if (!FUSED) {
        float* w = dst + ((size_t)(b * 32 + r0 + r) * NH + h) * NE + e0;
        *(float4*)w       = oA;
        *(float4*)(w + 4) = oB;
    } else {
        const int i = r0 + r;  // intra row 0..127
        const float* wi = vinter + ((size_t)(b * 32 + (i >> 2)) * NH + h) * NE + e0;
        const float4 iA = *(const float4*)wi;
        const float4 iB = *(const float4*)(wi + 4);
        oA.x += iA.x; oA.y += iA.y; oA.z += iA.z; oA.w += iA.w;
        oB.x += iB.x; oB.y += iB.y; oB.z += iB.z; oB.w += iB.w;
        float* ob = dst + ((size_t)(b * 4096 + i * 32) * NH + h) * NE + e0;
        #pragma unroll
        for (int j = 0; j < 32; j++) {
            *(float4*)(ob + (size_t)j * ROWSTRIDE)     = oA;
            *(float4*)(ob + (size_t)j * ROWSTRIDE + 4) = oB;
        }
    }
}

extern "C" void kernel_launch(void* const* d_in, const int* in_sizes, int n_in,
                              void* d_out, int out_size, void* d_ws, size_t ws_size,
                              hipStream_t stream) {
    const float* q_inter = (const float*)d_in[0];
    const float* k_inter = (const float*)d_in[1];
    const float* v_inter = (const float*)d_in[2];
    const float* q_intra = (const float*)d_in[3];
    const float* k_intra = (const float*)d_in[4];
    const float* v_intra = (const float*)d_in[5];
    float* out = (float*)d_out;
    float* ws  = (float*)d_ws;   // V_inter: [16,32,8,64] fp32 = 1 MiB

    // Kernel 1: inter attention -> ws. Grid = B*H = 128 blocks.
    attn_kernel<32, false><<<16 * 8, 256, 0, stream>>>(
        q_inter, k_inter, v_inter, ws, nullptr);

    // Kernel 2: intra attention fused with upsample-add -> out.
    // Grid = B*H*(128/32) = 512 blocks.
    attn_kernel<128, true><<<16 * 8 * 4, 256, 0, stream>>>(
        q_intra, k_intra, v_intra, out, ws);
}